// Round 3
// baseline (251.686 us; speedup 1.0000x reference)
//
#include <hip/hip_runtime.h>
#include <math.h>

// Problem constants (fixed by setup_inputs): x is (8,1024,1024,2) fp32, k=61
#define NB 8
#define HH 1024
#define WW 1024
#define CC 2
#define RAD 30
#define KS 61
#define ROWSZ (WW * CC)        /* 2048 floats per row */
#define IMGSZ (HH * ROWSZ)     /* 2097152 floats per image */
#define STR4 (ROWSZ / 4)       /* 512 float4 per row */
#define NCOL4 (NB * STR4)      /* 4096 independent float4 columns */
#define VSEGH 32
#define VNSEG (HH / VSEGH)     /* 32 */
#define EPSV 1e-7f
#define SCALEV (1.0f / (float)(KS * KS * CC))  /* 1/7442, keras divides by k*k*C */
// LDS anti-bank-conflict padding: +1 float per 8
#define PDW (WW + WW / 8)
#define PD(i) ((i) + ((i) >> 3))

__device__ __forceinline__ float4 f4add(float4 a, float4 b) {
    return make_float4(a.x + b.x, a.y + b.y, a.z + b.z, a.w + b.w);
}
__device__ __forceinline__ float4 f4sub(float4 a, float4 b) {
    return make_float4(a.x - b.x, a.y - b.y, a.z - b.z, a.w - b.w);
}
__device__ __forceinline__ float4 f4fma(float4 a, float4 b, float4 c) {
    return make_float4(fmaf(a.x, b.x, c.x), fmaf(a.y, b.y, c.y),
                       fmaf(a.z, b.z, c.z), fmaf(a.w, b.w, c.w));
}

// ---------------------------------------------------------------------------
// K1: vertical box-sum (61-tap, zero-padded) of x. One float4 column strip per
// thread, 32-row segment. Interior segments (1..30) run a guard-free unroll-4
// body: 8 independent float4 loads batched -> 128B/thread in flight.
__global__ __launch_bounds__(256) void vbox_kernel(const float* __restrict__ in,
                                                   float* __restrict__ out) {
    int tid = blockIdx.x * 256 + threadIdx.x;
    int col = tid & (NCOL4 - 1);
    int seg = tid >> 12;               // tid / NCOL4
    int n = col >> 9;                  // col / STR4
    int w4 = col & (STR4 - 1);
    const float4* ip = (const float4*)(in + (size_t)n * IMGSZ) + w4;
    float4* op = (float4*)(out + (size_t)n * IMGSZ) + w4;
    int h0 = seg * VSEGH;
    float4 S = make_float4(0.f, 0.f, 0.f, 0.f);
    int lo = h0 - RAD; if (lo < 0) lo = 0;
    int hiex = h0 + RAD;
    int h = lo;
    for (; h + 4 <= hiex; h += 4) {
        float4 v0 = ip[(h + 0) * STR4];
        float4 v1 = ip[(h + 1) * STR4];
        float4 v2 = ip[(h + 2) * STR4];
        float4 v3 = ip[(h + 3) * STR4];
        S = f4add(S, f4add(f4add(v0, v1), f4add(v2, v3)));
    }
    for (; h < hiex; ++h) S = f4add(S, ip[h * STR4]);

    if (seg != 0 && seg != VNSEG - 1) {
        // interior: no boundary guards at all
        for (int ho = h0; ho < h0 + VSEGH; ho += 4) {
            float4 a0 = ip[(ho + 0 + RAD) * STR4];
            float4 a1 = ip[(ho + 1 + RAD) * STR4];
            float4 a2 = ip[(ho + 2 + RAD) * STR4];
            float4 a3 = ip[(ho + 3 + RAD) * STR4];
            float4 b0 = ip[(ho + 0 - RAD) * STR4];
            float4 b1 = ip[(ho + 1 - RAD) * STR4];
            float4 b2 = ip[(ho + 2 - RAD) * STR4];
            float4 b3 = ip[(ho + 3 - RAD) * STR4];
            S = f4add(S, a0); op[(ho + 0) * STR4] = S; S = f4sub(S, b0);
            S = f4add(S, a1); op[(ho + 1) * STR4] = S; S = f4sub(S, b1);
            S = f4add(S, a2); op[(ho + 2) * STR4] = S; S = f4sub(S, b2);
            S = f4add(S, a3); op[(ho + 3) * STR4] = S; S = f4sub(S, b3);
        }
    } else {
        const float4 Z = make_float4(0.f, 0.f, 0.f, 0.f);
        for (int ho = h0; ho < h0 + VSEGH; ho += 4) {
            float4 a[4], b[4];
            #pragma unroll
            for (int i = 0; i < 4; ++i) {
                int ha = ho + i + RAD;
                a[i] = (ha < HH) ? ip[ha * STR4] : Z;
            }
            #pragma unroll
            for (int i = 0; i < 4; ++i) {
                int hb = ho + i - RAD;
                b[i] = (hb >= 0) ? ip[hb * STR4] : Z;
            }
            #pragma unroll
            for (int i = 0; i < 4; ++i) {
                S = f4add(S, a[i]);
                op[(ho + i) * STR4] = S;
                S = f4sub(S, b[i]);
            }
        }
    }
}

// K3: vertical dual box-sum of out and out*out (read 'out' once per tap).
__global__ __launch_bounds__(256) void vbox2_kernel(const float* __restrict__ in,
                                                    float* __restrict__ o1,
                                                    float* __restrict__ o2) {
    int tid = blockIdx.x * 256 + threadIdx.x;
    int col = tid & (NCOL4 - 1);
    int seg = tid >> 12;
    int n = col >> 9;
    int w4 = col & (STR4 - 1);
    const float4* ip = (const float4*)(in + (size_t)n * IMGSZ) + w4;
    float4* p1 = (float4*)(o1 + (size_t)n * IMGSZ) + w4;
    float4* p2 = (float4*)(o2 + (size_t)n * IMGSZ) + w4;
    int h0 = seg * VSEGH;
    float4 S = make_float4(0.f, 0.f, 0.f, 0.f);
    float4 Q = make_float4(0.f, 0.f, 0.f, 0.f);
    int lo = h0 - RAD; if (lo < 0) lo = 0;
    int hiex = h0 + RAD;
    int h = lo;
    for (; h + 4 <= hiex; h += 4) {
        float4 v0 = ip[(h + 0) * STR4];
        float4 v1 = ip[(h + 1) * STR4];
        float4 v2 = ip[(h + 2) * STR4];
        float4 v3 = ip[(h + 3) * STR4];
        S = f4add(S, f4add(f4add(v0, v1), f4add(v2, v3)));
        Q = f4fma(v0, v0, Q); Q = f4fma(v1, v1, Q);
        Q = f4fma(v2, v2, Q); Q = f4fma(v3, v3, Q);
    }
    for (; h < hiex; ++h) {
        float4 v = ip[h * STR4];
        S = f4add(S, v); Q = f4fma(v, v, Q);
    }

    if (seg != 0 && seg != VNSEG - 1) {
        for (int ho = h0; ho < h0 + VSEGH; ho += 4) {
            float4 a0 = ip[(ho + 0 + RAD) * STR4];
            float4 a1 = ip[(ho + 1 + RAD) * STR4];
            float4 a2 = ip[(ho + 2 + RAD) * STR4];
            float4 a3 = ip[(ho + 3 + RAD) * STR4];
            float4 b0 = ip[(ho + 0 - RAD) * STR4];
            float4 b1 = ip[(ho + 1 - RAD) * STR4];
            float4 b2 = ip[(ho + 2 - RAD) * STR4];
            float4 b3 = ip[(ho + 3 - RAD) * STR4];
            S = f4add(S, a0); Q = f4fma(a0, a0, Q);
            p1[(ho + 0) * STR4] = S; p2[(ho + 0) * STR4] = Q;
            S = f4sub(S, b0); Q = make_float4(fmaf(-b0.x, b0.x, Q.x), fmaf(-b0.y, b0.y, Q.y), fmaf(-b0.z, b0.z, Q.z), fmaf(-b0.w, b0.w, Q.w));
            S = f4add(S, a1); Q = f4fma(a1, a1, Q);
            p1[(ho + 1) * STR4] = S; p2[(ho + 1) * STR4] = Q;
            S = f4sub(S, b1); Q = make_float4(fmaf(-b1.x, b1.x, Q.x), fmaf(-b1.y, b1.y, Q.y), fmaf(-b1.z, b1.z, Q.z), fmaf(-b1.w, b1.w, Q.w));
            S = f4add(S, a2); Q = f4fma(a2, a2, Q);
            p1[(ho + 2) * STR4] = S; p2[(ho + 2) * STR4] = Q;
            S = f4sub(S, b2); Q = make_float4(fmaf(-b2.x, b2.x, Q.x), fmaf(-b2.y, b2.y, Q.y), fmaf(-b2.z, b2.z, Q.z), fmaf(-b2.w, b2.w, Q.w));
            S = f4add(S, a3); Q = f4fma(a3, a3, Q);
            p1[(ho + 3) * STR4] = S; p2[(ho + 3) * STR4] = Q;
            S = f4sub(S, b3); Q = make_float4(fmaf(-b3.x, b3.x, Q.x), fmaf(-b3.y, b3.y, Q.y), fmaf(-b3.z, b3.z, Q.z), fmaf(-b3.w, b3.w, Q.w));
        }
    } else {
        const float4 Z = make_float4(0.f, 0.f, 0.f, 0.f);
        for (int ho = h0; ho < h0 + VSEGH; ho += 4) {
            float4 a[4], b[4];
            #pragma unroll
            for (int i = 0; i < 4; ++i) {
                int ha = ho + i + RAD;
                a[i] = (ha < HH) ? ip[ha * STR4] : Z;
            }
            #pragma unroll
            for (int i = 0; i < 4; ++i) {
                int hb = ho + i - RAD;
                b[i] = (hb >= 0) ? ip[hb * STR4] : Z;
            }
            #pragma unroll
            for (int i = 0; i < 4; ++i) {
                S = f4add(S, a[i]); Q = f4fma(a[i], a[i], Q);
                p1[(ho + i) * STR4] = S; p2[(ho + i) * STR4] = Q;
                S = f4sub(S, b[i]);
                Q = make_float4(fmaf(-b[i].x, b[i].x, Q.x), fmaf(-b[i].y, b[i].y, Q.y),
                                fmaf(-b[i].z, b[i].z, Q.z), fmaf(-b[i].w, b[i].w, Q.w));
            }
        }
    }
}

__device__ inline float wave_incl_scan(float v) {
    int lane = threadIdx.x & 63;
    #pragma unroll
    for (int d = 1; d < 64; d <<= 1) {
        float o = __shfl_up(v, d, 64);
        if (lane >= d) v += o;
    }
    return v;
}

// K2: horizontal box of vertical sums (prefix-sum per row) + out = x - s*box.
// One block per (n,h) row. float4 global I/O; padded LDS for the scan.
__global__ __launch_bounds__(256) void hbox_sub_kernel(const float* __restrict__ vsum,
                                                       const float* __restrict__ x,
                                                       float* __restrict__ out) {
    __shared__ float ch[2][PDW];
    __shared__ float wtot[4];
    int t = threadIdx.x;
    size_t g = (size_t)blockIdx.x * ROWSZ;
    const float4* vrow = (const float4*)(vsum + g);
    #pragma unroll
    for (int i = 0; i < 2; ++i) {
        int j = t + 256 * i;
        float4 v = vrow[j];
        ch[0][PD(2 * j)] = v.x;     ch[1][PD(2 * j)] = v.y;
        ch[0][PD(2 * j + 1)] = v.z; ch[1][PD(2 * j + 1)] = v.w;
    }
    __syncthreads();
    // per-thread serial chunk of 8 + wave scan of partials (2 waves/channel)
    int c = t >> 7, j = t & 127, base = j * 8;
    float v[8]; float run = 0.f;
    #pragma unroll
    for (int i = 0; i < 8; ++i) { run += ch[c][PD(base + i)]; v[i] = run; }
    float incl = wave_incl_scan(run);
    int wid = t >> 6;
    if ((t & 63) == 63) wtot[wid] = incl;
    __syncthreads();
    float off = incl - run;
    if (wid & 1) off += wtot[wid - 1];
    #pragma unroll
    for (int i = 0; i < 8; ++i) ch[c][PD(base + i)] = off + v[i];
    __syncthreads();
    // box(w) = P[min(w+30,1023)] - (w>=31 ? P[w-31] : 0)
    const float4* xrow = (const float4*)(x + g);
    float4* orow = (float4*)(out + g);
    #pragma unroll
    for (int i = 0; i < 2; ++i) {
        int jj = t + 256 * i;
        int w0 = 2 * jj, w1 = 2 * jj + 1;
        int hi0 = w0 + RAD; if (hi0 > WW - 1) hi0 = WW - 1;
        int hi1 = w1 + RAD; if (hi1 > WW - 1) hi1 = WW - 1;
        int lo0 = w0 - RAD - 1, lo1 = w1 - RAD - 1;
        float s00 = ch[0][PD(hi0)], s10 = ch[1][PD(hi0)];
        if (lo0 >= 0) { s00 -= ch[0][PD(lo0)]; s10 -= ch[1][PD(lo0)]; }
        float s01 = ch[0][PD(hi1)], s11 = ch[1][PD(hi1)];
        if (lo1 >= 0) { s01 -= ch[0][PD(lo1)]; s11 -= ch[1][PD(lo1)]; }
        float4 xv = xrow[jj];
        float4 o;
        o.x = xv.x - SCALEV * s00; o.y = xv.y - SCALEV * s10;
        o.z = xv.z - SCALEV * s01; o.w = xv.w - SCALEV * s11;
        orow[jj] = o;
    }
}

// K4: horizontal box of both vertical sums + finalize y = out/(sqrt(c2-c1^2)+eps).
__global__ __launch_bounds__(256) void hbox_final_kernel(const float* __restrict__ s1v,
                                                         const float* __restrict__ s2v,
                                                         float* __restrict__ out) {
    __shared__ float ch[4][PDW];   // [0..1]=sum channels, [2..3]=sumsq channels
    int t = threadIdx.x;
    size_t g = (size_t)blockIdx.x * ROWSZ;
    const float4* arow = (const float4*)(s1v + g);
    const float4* brow = (const float4*)(s2v + g);
    #pragma unroll
    for (int i = 0; i < 2; ++i) {
        int j = t + 256 * i;
        float4 a = arow[j];
        ch[0][PD(2 * j)] = a.x;     ch[1][PD(2 * j)] = a.y;
        ch[0][PD(2 * j + 1)] = a.z; ch[1][PD(2 * j + 1)] = a.w;
        float4 b = brow[j];
        ch[2][PD(2 * j)] = b.x;     ch[3][PD(2 * j)] = b.y;
        ch[2][PD(2 * j + 1)] = b.z; ch[3][PD(2 * j + 1)] = b.w;
    }
    __syncthreads();
    // 4 arrays x 64 chunks of 16; one wave per array -> wave scan only
    int a = t >> 6, j = t & 63, base = j * 16;
    float v[16]; float run = 0.f;
    #pragma unroll
    for (int i = 0; i < 16; ++i) { run += ch[a][PD(base + i)]; v[i] = run; }
    float incl = wave_incl_scan(run);
    float off = incl - run;
    #pragma unroll
    for (int i = 0; i < 16; ++i) ch[a][PD(base + i)] = off + v[i];
    __syncthreads();
    float4* orow = (float4*)(out + g);
    #pragma unroll
    for (int i = 0; i < 2; ++i) {
        int jj = t + 256 * i;
        int w0 = 2 * jj, w1 = 2 * jj + 1;
        int hi0 = w0 + RAD; if (hi0 > WW - 1) hi0 = WW - 1;
        int hi1 = w1 + RAD; if (hi1 > WW - 1) hi1 = WW - 1;
        int lo0 = w0 - RAD - 1, lo1 = w1 - RAD - 1;
        float s1a = ch[0][PD(hi0)], s1b = ch[1][PD(hi0)];
        float s2a = ch[2][PD(hi0)], s2b = ch[3][PD(hi0)];
        if (lo0 >= 0) {
            s1a -= ch[0][PD(lo0)]; s1b -= ch[1][PD(lo0)];
            s2a -= ch[2][PD(lo0)]; s2b -= ch[3][PD(lo0)];
        }
        float s1c = ch[0][PD(hi1)], s1d = ch[1][PD(hi1)];
        float s2c = ch[2][PD(hi1)], s2d = ch[3][PD(hi1)];
        if (lo1 >= 0) {
            s1c -= ch[0][PD(lo1)]; s1d -= ch[1][PD(lo1)];
            s2c -= ch[2][PD(lo1)]; s2d -= ch[3][PD(lo1)];
        }
        float4 ov = orow[jj];
        float c1, c2, var;
        float4 r;
        c1 = SCALEV * s1a; c2 = SCALEV * s2a; var = c2 - c1 * c1;
        r.x = ov.x / (sqrtf(fmaxf(var, 0.f)) + EPSV);
        c1 = SCALEV * s1b; c2 = SCALEV * s2b; var = c2 - c1 * c1;
        r.y = ov.y / (sqrtf(fmaxf(var, 0.f)) + EPSV);
        c1 = SCALEV * s1c; c2 = SCALEV * s2c; var = c2 - c1 * c1;
        r.z = ov.z / (sqrtf(fmaxf(var, 0.f)) + EPSV);
        c1 = SCALEV * s1d; c2 = SCALEV * s2d; var = c2 - c1 * c1;
        r.w = ov.w / (sqrtf(fmaxf(var, 0.f)) + EPSV);
        orow[jj] = r;
    }
}

extern "C" void kernel_launch(void* const* d_in, const int* in_sizes, int n_in,
                              void* d_out, int out_size, void* d_ws, size_t ws_size,
                              hipStream_t stream) {
    const float* x = (const float*)d_in[0];
    float* out = (float*)d_out;
    float* wsf = (float*)d_ws;
    float* V1 = wsf;                              // 64 MB: vert box sums (reused)
    float* V3 = wsf + (size_t)NB * IMGSZ;         // 64 MB: vert box of out^2

    // out = x - s * Box(x)
    vbox_kernel<<<(NCOL4 * VNSEG) / 256, 256, 0, stream>>>(x, V1);
    hbox_sub_kernel<<<NB * HH, 256, 0, stream>>>(V1, x, out);
    // c1 = s*Box(out), c2 = s*Box(out^2); y = out / (sqrt(c2-c1^2)+eps)
    vbox2_kernel<<<(NCOL4 * VNSEG) / 256, 256, 0, stream>>>(out, V1, V3);
    hbox_final_kernel<<<NB * HH, 256, 0, stream>>>(V1, V3, out);
}